// Round 12
// baseline (1394.390 us; speedup 1.0000x reference)
//
#include <hip/hip_runtime.h>
#include <hip/hip_bf16.h>
#include <cstdint>

#define B_   2048
#define H_   512
#define T_   128
#define V_   64
#define FOURH 2048

typedef __bf16 bf16x8 __attribute__((ext_vector_type(8)));
typedef float  floatx4 __attribute__((ext_vector_type(4)));
typedef int    intx4   __attribute__((ext_vector_type(4)));

__device__ __forceinline__ unsigned short f2bf(float f) {
    union { float f; uint32_t u; } v; v.f = f;
    uint32_t r = v.u + 0x7fff + ((v.u >> 16) & 1);
    return (unsigned short)(r >> 16);
}

__device__ __forceinline__ float rcp_(float x) {
    float r; asm("v_rcp_f32 %0, %1" : "=v"(r) : "v"(x)); return r;
}
__device__ __forceinline__ float sigmoidf_(float x) {
    return rcp_(1.0f + __expf(-x));
}
__device__ __forceinline__ float tanhf_(float x) {
    float e = __expf(fminf(-2.0f * x, 80.0f));
    return (1.0f - e) * rcp_(1.0f + e);
}

__device__ __forceinline__ void global_to_lds16(const unsigned short* g, unsigned short* l) {
    __builtin_amdgcn_global_load_lds(
        (const __attribute__((address_space(1))) unsigned int*)g,
        (__attribute__((address_space(3))) unsigned int*)l, 16, 0, 0);
}

// System-coherent 16B load (bypass L1+L2), blocking. R1-proven.
__device__ __forceinline__ bf16x8 load16_sys(const unsigned short* p) {
    bf16x8 d;
    asm volatile("global_load_dwordx4 %0, %1, off sc0 sc1\n\t"
                 "s_waitcnt vmcnt(0)"
                 : "=v"(d) : "v"(p));
    return d;
}

// ---------------------------------------------------------------------------
// Flag sync — sc0 sc1 both directions (only verified-correct flavor).
// Steady-state posts are NO-DRAIN (R11-verified): data stores are issued
// before the flag store; consumer samples trail flag visibility by
// detect + load-RT. Prologue/epilogue posts keep real drains.
// ---------------------------------------------------------------------------
__device__ __forceinline__ void flag_prefetch(const unsigned int* fp, intx4& f) {
    asm volatile("global_load_dwordx4 %0, %1, off sc0 sc1"
                 : "=v"(f) : "v"(fp) : "memory");
}
__device__ __forceinline__ bool flag_ok(const intx4& f, unsigned int tgt) {
    return (unsigned int)f[0] >= tgt && (unsigned int)f[1] >= tgt &&
           (unsigned int)f[2] >= tgt && (unsigned int)f[3] >= tgt;
}
__device__ __forceinline__ void wait4(const unsigned int* fp, unsigned int tgt) {
    for (;;) {
        intx4 f;
        asm volatile("global_load_dwordx4 %0, %1, off sc0 sc1\n\t"
                     "s_waitcnt vmcnt(0)" : "=v"(f) : "v"(fp) : "memory");
        if (flag_ok(f, tgt)) return;
        __builtin_amdgcn_s_sleep(1);
    }
}
__device__ __forceinline__ void flag_post(unsigned int* p, unsigned int v) {
    asm volatile("global_store_dword %0, %1, off sc0 sc1" :: "v"(p), "v"(v) : "memory");
}

// ---------------------------------------------------------------------------
// prep: permuted bf16 weights, bf16 z / fc_w, fused permuted bias, zero flags.
// ---------------------------------------------------------------------------
__global__ void prep_kernel(const float* __restrict__ z,
                            const float* __restrict__ w_ih,
                            const float* __restrict__ w_hh,
                            const float* __restrict__ b_ih,
                            const float* __restrict__ b_hh,
                            const float* __restrict__ fc_w,
                            unsigned short* __restrict__ Bp_ih,
                            unsigned short* __restrict__ Bp_hh,
                            unsigned short* __restrict__ z_bf,
                            unsigned short* __restrict__ fcw_bf,
                            float* __restrict__ biasp,
                            unsigned int* __restrict__ cnt) {
    int i = blockIdx.x * blockDim.x + threadIdx.x;   // 2048*512 threads
    int col = i >> 9, k = i & 511;
    int jj = col >> 7, cc = col & 127;
    int gate = (cc >> 4) & 3;
    int hcl = ((cc >> 6) << 4) | (cc & 15);
    int p = gate * 512 + jj * 32 + hcl;
    Bp_hh[i] = f2bf(w_hh[p * 512 + k]);
    Bp_ih[i] = f2bf(w_ih[p * 512 + k]);
    z_bf[i]  = f2bf(z[i]);
    if (i < V_ * H_) fcw_bf[i] = f2bf(fc_w[i]);
    if (i < FOURH) {
        int j2 = i >> 7, c2 = i & 127;
        int g2 = (c2 >> 4) & 3;
        int h2 = ((c2 >> 6) << 4) | (c2 & 15);
        int p2 = g2 * 512 + j2 * 32 + h2;
        biasp[i] = b_ih[p2] + b_hh[p2];
    }
    // 32 groups x 64 uints: [s*8+j] for slice s=0..3. Zero all.
    if (i < 2048) cnt[i] = 0;
}

// ---------------------------------------------------------------------------
// Round-1-proven 128x128 (K=512, BK=64) tile core for the x-gates GEMM.
// ---------------------------------------------------------------------------
__device__ __forceinline__ void gemm_tile_r1(
        const unsigned short* __restrict__ Aglob,
        const unsigned short* __restrict__ Bglob,
        int arow0, int brow0,
        unsigned short* As, unsigned short* Bs,
        floatx4 acc[2][8], int w, int l) {
    const int lr = l >> 3;
    const int gl = (l & 7) ^ lr;
    const int ln = l & 15, lq = l >> 4, ls = l & 7;
    for (int kc = 0; kc < 8; ++kc) {
        const int kof = kc * 64 + gl * 8;
        #pragma unroll
        for (int q = 0; q < 4; ++q) {
            const int r0 = (w * 4 + q) * 8;
            global_to_lds16(Aglob + (size_t)(arow0 + r0 + lr) * 512 + kof, As + r0 * 64);
            global_to_lds16(Bglob + (size_t)(brow0 + r0 + lr) * 512 + kof, Bs + r0 * 64);
        }
        __syncthreads();
        #pragma unroll
        for (int kk = 0; kk < 2; ++kk) {
            bf16x8 a[2], b[8];
            #pragma unroll
            for (int mt = 0; mt < 2; ++mt) {
                const int m = 32 * w + 16 * mt + ln;
                const int g = kk * 4 + lq;
                a[mt] = *(const bf16x8*)(As + m * 64 + ((g ^ ls) * 8));
            }
            #pragma unroll
            for (int nt = 0; nt < 8; ++nt) {
                const int n = 16 * nt + ln;
                const int g = kk * 4 + lq;
                b[nt] = *(const bf16x8*)(Bs + n * 64 + ((g ^ ls) * 8));
            }
            #pragma unroll
            for (int mt = 0; mt < 2; ++mt)
                #pragma unroll
                for (int nt = 0; nt < 8; ++nt)
                    acc[mt][nt] = __builtin_amdgcn_mfma_f32_16x16x32_bf16(
                        a[mt], b[nt], acc[mt][nt], 0, 0, 0);
        }
        __syncthreads();
    }
}

__global__ void __launch_bounds__(256) xg_gemm_kernel(
        const unsigned short* __restrict__ z_bf,
        const unsigned short* __restrict__ Bp_ih,
        const float* __restrict__ biasp,
        float* __restrict__ xg) {
    __shared__ unsigned short As[128 * 64];
    __shared__ unsigned short Bs[128 * 64];
    const int bi = blockIdx.x, j = blockIdx.y;
    const int tid = threadIdx.x, w = tid >> 6, l = tid & 63;
    floatx4 acc[2][8];
    const floatx4 zf = {0.f, 0.f, 0.f, 0.f};
    for (int a1 = 0; a1 < 2; ++a1) for (int a2 = 0; a2 < 8; ++a2) acc[a1][a2] = zf;

    gemm_tile_r1(z_bf, Bp_ih, bi * 128, j * 128, As, Bs, acc, w, l);

    const int ln = l & 15, lq = l >> 4;
    #pragma unroll
    for (int mt = 0; mt < 2; ++mt)
        #pragma unroll
        for (int nt = 0; nt < 8; ++nt) {
            const int colp = j * 128 + nt * 16 + ln;
            const float bv = biasp[colp];
            #pragma unroll
            for (int r = 0; r < 4; ++r) {
                const int b = bi * 128 + 32 * w + 16 * mt + lq * 4 + r;
                xg[(size_t)b * FOURH + colp] = acc[mt][nt][r] + bv;
            }
        }
}

// ---------------------------------------------------------------------------
// 16-row slice staging: tile = 16 rows x 512 K-cols bf16 = 16 KB.
// Thread (w,l): row r = w*4 + (l>>4); il = l&15; slot = il&7;
// 4 loads i: block kc = i*2 + (il>>3); source granule = slot ^ (r&7).
// LDS layout: [kc][row][slot] (kc*1024 + r*64 + slot*8 ushorts) — matches
// the MFMA read af = lds + (s>>1)*1024 + ln*64 + ((ga ^ (ln&7))*8).
// ---------------------------------------------------------------------------
__device__ __forceinline__ void issue_slice(const unsigned short* __restrict__ src,
                                            int w, int l, intx4 (&u)[4]) {
    const int r = w * 4 + (l >> 4);
    const int il = l & 15, slot = il & 7;
    #pragma unroll
    for (int i = 0; i < 4; ++i) {
        const int kc = i * 2 + (il >> 3);
        const unsigned short* p = src + (size_t)r * 512 + kc * 64 + ((slot ^ (r & 7)) * 8);
        asm volatile("global_load_dwordx4 %0, %1, off sc0 sc1"
                     : "=&v"(u[i]) : "v"(p) : "memory");
    }
}

// ---------------------------------------------------------------------------
// 4-slice pipelined phase. Slice X (16 rows) is an independent LSTM chain.
// Per phase: commit staged X -> MFMA -> single vmcnt(0) -> confirm flags for
// slice Z=(X+2) (prefetched LAST phase) -> issue Z's loads (consumed 2
// phases later) -> out[t-1] (quarter j==X) -> prefetch next flags -> gates
// -> h-store -> no-drain flag post. All waits are vmcnt(0) + proven polls.
// Anti-dep: peer posts flag_X = t only after its prior-phase vmcnt(0)
// retired its reads of h_X(t-2); we confirm all 8 flag_X >= t two phases
// before overwriting h_X in hbuf[t&1].
// ---------------------------------------------------------------------------
template<int X>
__device__ __forceinline__ void phase4(
        int t,
        int arow0, int j, int tid, int w, int l, int ln, int lq,
        unsigned short* h0b, unsigned short* h1b,
        unsigned int* flagp,
        unsigned short* Xlds, unsigned short* hlds,
        const unsigned short* __restrict__ fcw_bf,
        const bf16x8 (&bq)[16][4],
        float (&cst)[4], const floatx4 (&xga)[4],
        float fcb_v, int v, float* __restrict__ out,
        intx4 (&u)[4], intx4& fpA, intx4& fpB)
{
    constexpr int Z   = (X + 2) & 3;   // slice whose loads we issue
    constexpr int DZ  = (X + 2) >> 2;  // its step = t + DZ
    constexpr int Zn  = (X + 3) & 3;   // prefetch target for next phase
    constexpr int DZn = (X + 3) >> 2;
    const bool mine = (j == X);
    const floatx4 zf = {0.f, 0.f, 0.f, 0.f};

    // P1: commit staged slice X (h_X(t-1)) -> LDS
    {
        const int r = w * 4 + lq;
        const int il = l & 15, slot = il & 7;
        #pragma unroll
        for (int i = 0; i < 4; ++i) {
            const int kc = i * 2 + (il >> 3);
            *(intx4*)(Xlds + kc * 1024 + r * 64 + slot * 8) = u[i];
        }
    }
    __syncthreads();

    // P2: MFMA slice X step t (64 gate + 16 projection MFMA; ap == af)
    floatx4 acc[4];
    #pragma unroll
    for (int nt = 0; nt < 4; ++nt) acc[nt] = zf;
    floatx4 pacc = zf;
    #pragma unroll
    for (int s = 0; s < 16; ++s) {
        const int ga = (s & 1) * 4 + lq;
        const unsigned short* Ac = Xlds + (s >> 1) * 1024;
        bf16x8 af = *(const bf16x8*)(Ac + ln * 64 + ((ga ^ (ln & 7)) * 8));
        #pragma unroll
        for (int nt = 0; nt < 4; ++nt)
            acc[nt] = __builtin_amdgcn_mfma_f32_16x16x32_bf16(
                af, bq[s][nt], acc[nt], 0, 0, 0);
        if (mine) {
            bf16x8 bp = *(const bf16x8*)(fcw_bf + (size_t)v * 512 + s * 32 + lq * 8);
            pacc = __builtin_amdgcn_mfma_f32_16x16x32_bf16(af, bp, pacc, 0, 0, 0);
        }
    }

    // P3: single drain; confirm; issue Z loads; out; prefetch next flags
    asm volatile("s_waitcnt vmcnt(0)" ::: "memory");
    __builtin_amdgcn_sched_barrier(0);
    if (t + DZ < T_) {
        const unsigned int tz = (unsigned int)(t + DZ);
        if (!(flag_ok(fpA, tz) && flag_ok(fpB, tz))) {
            wait4(flagp + Z * 8,     tz);
            wait4(flagp + Z * 8 + 4, tz);
        }
        const unsigned short* src = (((t + DZ - 1) & 1) ? h1b : h0b)
                                  + (size_t)(arow0 + Z * 16) * 512;
        issue_slice(src, w, l, u);
    }
    if (mine) {
        #pragma unroll
        for (int r = 0; r < 4; ++r) {
            const int b = arow0 + j * 16 + lq * 4 + r;
            out[(size_t)b * (T_ * V_) + (t - 1) * V_ + v] = fmaxf(pacc[r] + fcb_v, 0.0f);
        }
    }
    if (t + DZn < T_) {
        flag_prefetch(flagp + Zn * 8,     fpA);
        flag_prefetch(flagp + Zn * 8 + 4, fpB);
    }

    // P4: gates -> h_X(t); store; no-drain flag post
    #pragma unroll
    for (int r = 0; r < 4; ++r) {
        float iv = sigmoidf_(acc[0][r] + xga[0][r]);
        float fv = sigmoidf_(acc[1][r] + xga[1][r]);
        float gv = tanhf_  (acc[2][r] + xga[2][r]);
        float ov = sigmoidf_(acc[3][r] + xga[3][r]);
        float cn = fv * cst[r] + iv * gv;
        cst[r] = cn;
        hlds[(lq * 4 + r) * 64 + (16 * w + ln)] = f2bf(ov * tanhf_(cn));
    }
    __syncthreads();
    if (tid < 128) {
        const int row = tid >> 3, seg = tid & 7;
        intx4 d = *(const intx4*)(hlds + row * 64 + seg * 8);
        unsigned short* hn = (t & 1) ? h1b : h0b;
        const unsigned short* p = hn + (size_t)(arow0 + X * 16 + row) * 512 + j * 64 + seg * 8;
        asm volatile("global_store_dwordx4 %0, %1, off sc0 sc1" :: "v"(p), "v"(d) : "memory");
    }
    __syncthreads();
    if (tid == 0) flag_post(flagp + X * 8 + j, (unsigned int)(t + 1));
}

// ---------------------------------------------------------------------------
// Persistent LSTM, 32 groups x 8 WGs, 64 rows x 256 cols per WG, rows split
// into FOUR independent 16-row slice-chains, phases a quarter-step apart.
// ---------------------------------------------------------------------------
__global__ void __launch_bounds__(256, 1) lstm_persistent(
        const unsigned short* __restrict__ Bp_hh,
        const unsigned short* __restrict__ fcw_bf,
        const float* __restrict__ xg,
        const float* __restrict__ fc_b,
        unsigned short* __restrict__ h0b,
        unsigned short* __restrict__ h1b,
        unsigned int* __restrict__ cnt,
        float* __restrict__ out) {
    __shared__ unsigned short lds0[8 * 1024];   // 16 KiB slice tile (even phases)
    __shared__ unsigned short lds1[8 * 1024];   // 16 KiB slice tile (odd phases)
    __shared__ unsigned short hlds[1024];       //  2 KiB h transpose buffer

    const int bx = blockIdx.x;
    const int gi = bx & 31;
    const int j  = bx >> 5;                // 0..7
    const int tid = threadIdx.x;
    const int w = tid >> 6, l = tid & 63;
    const int ln = l & 15, lq = l >> 4;
    const bool jlt4 = (j < 4);
    const int v = 16 * w + ln;
    const float fcb_v = fc_b[v];
    const int arow0 = gi * 64;
    const int colbase = j * 256 + (w >> 1) * 128 + (w & 1) * 64;
    unsigned int* flagp = cnt + gi * 64;   // [s*8 + j], s = 0..3
    const floatx4 zf = {0.f, 0.f, 0.f, 0.f};

    // ---- recurrent-weight fragments in registers (persistent) ----
    bf16x8 bq[16][4];
    {
        const unsigned short* bbase =
            Bp_hh + ((size_t)(colbase + ln)) * 512 + lq * 8;
        #pragma unroll
        for (int s = 0; s < 16; ++s)
            #pragma unroll
            for (int nt = 0; nt < 4; ++nt)
                bq[s][nt] = *(const bf16x8*)(bbase + (size_t)nt * 16 * 512 + s * 32);
    }

    // ---- x-gate tiles into registers, split into 4 slices ----
    floatx4 xga0[4], xga1[4], xga2[4], xga3[4];
    #pragma unroll
    for (int nt = 0; nt < 4; ++nt)
        #pragma unroll
        for (int r = 0; r < 4; ++r) {
            const int rb = lq * 4 + r;
            xga0[nt][r] = xg[(size_t)(arow0 +      rb) * FOURH + colbase + 16 * nt + ln];
            xga1[nt][r] = xg[(size_t)(arow0 + 16 + rb) * FOURH + colbase + 16 * nt + ln];
            xga2[nt][r] = xg[(size_t)(arow0 + 32 + rb) * FOURH + colbase + 16 * nt + ln];
            xga3[nt][r] = xg[(size_t)(arow0 + 48 + rb) * FOURH + colbase + 16 * nt + ln];
        }

    // ---- group stagger (R9): gi * ~0.4us one-time ----
    for (int d = 0; d < gi; ++d) __builtin_amdgcn_s_sleep(15);

    // ---- t = 0 for all 4 slices: c0 = 0 -> h0 ----
    float cst0[4], cst1[4], cst2[4], cst3[4];
#define PRO_SLICE(S, XGA, CST)                                                \
    {                                                                         \
        _Pragma("unroll")                                                     \
        for (int r = 0; r < 4; ++r) {                                         \
            float iv = sigmoidf_(XGA[0][r]);                                  \
            float gv = tanhf_  (XGA[2][r]);                                   \
            float ov = sigmoidf_(XGA[3][r]);                                  \
            float cv = iv * gv;                                               \
            CST[r] = cv;                                                      \
            hlds[(lq * 4 + r) * 64 + (16 * w + ln)] = f2bf(ov * tanhf_(cv));  \
        }                                                                     \
        __syncthreads();                                                      \
        if (tid < 128) {                                                      \
            const int row = tid >> 3, seg = tid & 7;                          \
            intx4 d = *(const intx4*)(hlds + row * 64 + seg * 8);             \
            const unsigned short* p = h0b                                     \
                + (size_t)(arow0 + S * 16 + row) * 512 + j * 64 + seg * 8;    \
            asm volatile("global_store_dwordx4 %0, %1, off sc0 sc1"           \
                         :: "v"(p), "v"(d) : "memory");                       \
        }                                                                     \
        __syncthreads();                                                      \
    }
    PRO_SLICE(0, xga0, cst0)
    PRO_SLICE(1, xga1, cst1)
    PRO_SLICE(2, xga2, cst2)
    PRO_SLICE(3, xga3, cst3)
#undef PRO_SLICE
    asm volatile("s_waitcnt vmcnt(0)" ::: "memory");   // prologue keeps drain
    __syncthreads();
    if (tid == 0) {
        flag_post(flagp +  0 + j, 1u);
        flag_post(flagp +  8 + j, 1u);
        flag_post(flagp + 16 + j, 1u);
        flag_post(flagp + 24 + j, 1u);
    }

    // gate slices 0,1; issue their loads; prefetch slice-2 flags
    wait4(flagp +  0, 1u); wait4(flagp +  4, 1u);
    wait4(flagp +  8, 1u); wait4(flagp + 12, 1u);
    intx4 uE[4], uO[4], fpA, fpB;
    issue_slice(h0b + (size_t)(arow0)      * 512, w, l, uE);   // slice 0
    issue_slice(h0b + (size_t)(arow0 + 16) * 512, w, l, uO);   // slice 1
    flag_prefetch(flagp + 16, fpA);                            // slice 2 flags
    flag_prefetch(flagp + 20, fpB);
    asm volatile("s_waitcnt vmcnt(0)" ::: "memory");           // first-phase init
    __builtin_amdgcn_sched_barrier(0);

    #pragma unroll 1
    for (int t = 1; t < T_; ++t) {
        phase4<0>(t, arow0, j, tid, w, l, ln, lq, h0b, h1b, flagp, lds0, hlds,
                  fcw_bf, bq, cst0, xga0, fcb_v, v, out, uE, fpA, fpB);
        phase4<1>(t, arow0, j, tid, w, l, ln, lq, h0b, h1b, flagp, lds1, hlds,
                  fcw_bf, bq, cst1, xga1, fcb_v, v, out, uO, fpA, fpB);
        phase4<2>(t, arow0, j, tid, w, l, ln, lq, h0b, h1b, flagp, lds0, hlds,
                  fcw_bf, bq, cst2, xga2, fcb_v, v, out, uE, fpA, fpB);
        phase4<3>(t, arow0, j, tid, w, l, ln, lq, h0b, h1b, flagp, lds1, hlds,
                  fcw_bf, bq, cst3, xga3, fcb_v, v, out, uO, fpA, fpB);
    }

    // ---- epilogue: drain, re-post final flags (durable) ----
    asm volatile("s_waitcnt vmcnt(0)" ::: "memory");
    __syncthreads();
    if (tid == 0) {
        flag_post(flagp +  0 + j, (unsigned int)T_);
        flag_post(flagp +  8 + j, (unsigned int)T_);
        flag_post(flagp + 16 + j, (unsigned int)T_);
        flag_post(flagp + 24 + j, (unsigned int)T_);
    }

    // ---- final projection of h_{T-1} (quarter j) ----
    if (jlt4) {
        wait4(flagp + j * 8,     (unsigned int)T_);
        wait4(flagp + j * 8 + 4, (unsigned int)T_);
        const unsigned short* hlast = h1b;        // (T_-1) & 1 = 1
        floatx4 pa = zf;
        const int ar = arow0 + j * 16 + ln;
        #pragma unroll
        for (int kc = 0; kc < 16; ++kc) {
            const int k = kc * 32 + lq * 8;
            bf16x8 a = load16_sys(hlast + (size_t)ar * 512 + k);
            bf16x8 b = *(const bf16x8*)(fcw_bf + (size_t)v * 512 + k);
            pa = __builtin_amdgcn_mfma_f32_16x16x32_bf16(a, b, pa, 0, 0, 0);
        }
        #pragma unroll
        for (int r = 0; r < 4; ++r) {
            const int b = arow0 + j * 16 + lq * 4 + r;
            out[(size_t)b * (T_ * V_) + (T_ - 1) * V_ + v] = fmaxf(pa[r] + fcb_v, 0.0f);
        }
    }
}

// ---------------------------------------------------------------------------
extern "C" void kernel_launch(void* const* d_in, const int* in_sizes, int n_in,
                              void* d_out, int out_size, void* d_ws, size_t ws_size,
                              hipStream_t stream) {
    const float* z    = (const float*)d_in[0];
    const float* w_ih = (const float*)d_in[1];
    const float* w_hh = (const float*)d_in[2];
    const float* b_ih = (const float*)d_in[3];
    const float* b_hh = (const float*)d_in[4];
    const float* fc_w = (const float*)d_in[5];
    const float* fc_b = (const float*)d_in[6];
    float* out = (float*)d_out;

    char* ws = (char*)d_ws;
    size_t o = 0;
    auto take = [&](size_t bytes) { char* p = ws + o; o += (bytes + 255) & ~(size_t)255; return p; };
    unsigned short* Bp_hh  = (unsigned short*)take((size_t)FOURH * H_ * 2);
    unsigned short* Bp_ih  = (unsigned short*)take((size_t)FOURH * H_ * 2);
    unsigned short* z_bf   = (unsigned short*)take((size_t)B_ * H_ * 2);
    unsigned short* fcw_bf = (unsigned short*)take((size_t)V_ * H_ * 2);
    float*          biasp  = (float*)take((size_t)FOURH * 4);
    unsigned short* hbuf0  = (unsigned short*)take((size_t)B_ * H_ * 2);
    unsigned short* hbuf1  = (unsigned short*)take((size_t)B_ * H_ * 2);
    unsigned int*   cnt    = (unsigned int*)take(32 * 256);   // 32 groups x 64 uints
    float*          xg     = (float*)take((size_t)B_ * FOURH * 4);

    prep_kernel<<<(B_ * H_) / 256, 256, 0, stream>>>(z, w_ih, w_hh, b_ih, b_hh, fc_w,
                                                     Bp_ih, Bp_hh, z_bf, fcw_bf, biasp, cnt);
    xg_gemm_kernel<<<dim3(16, 16), 256, 0, stream>>>(z_bf, Bp_ih, biasp, xg);
    lstm_persistent<<<256, 256, 0, stream>>>(Bp_hh, fcw_bf, xg, fc_b,
                                             hbuf0, hbuf1, cnt, out);
}

// Round 13
// 1273.575 us; speedup vs baseline: 1.0949x; 1.0949x over previous
//
#include <hip/hip_runtime.h>
#include <hip/hip_bf16.h>
#include <cstdint>

#define B_   2048
#define H_   512
#define T_   128
#define V_   64
#define FOURH 2048

typedef __bf16 bf16x8 __attribute__((ext_vector_type(8)));
typedef float  floatx4 __attribute__((ext_vector_type(4)));
typedef int    intx4   __attribute__((ext_vector_type(4)));

__device__ __forceinline__ unsigned short f2bf(float f) {
    union { float f; uint32_t u; } v; v.f = f;
    uint32_t r = v.u + 0x7fff + ((v.u >> 16) & 1);
    return (unsigned short)(r >> 16);
}

__device__ __forceinline__ float rcp_(float x) {
    float r; asm("v_rcp_f32 %0, %1" : "=v"(r) : "v"(x)); return r;
}
__device__ __forceinline__ float sigmoidf_(float x) {
    return rcp_(1.0f + __expf(-x));
}
__device__ __forceinline__ float tanhf_(float x) {
    float e = __expf(fminf(-2.0f * x, 80.0f));
    return (1.0f - e) * rcp_(1.0f + e);
}

__device__ __forceinline__ void global_to_lds16(const unsigned short* g, unsigned short* l) {
    __builtin_amdgcn_global_load_lds(
        (const __attribute__((address_space(1))) unsigned int*)g,
        (__attribute__((address_space(3))) unsigned int*)l, 16, 0, 0);
}

// System-coherent 16B load (bypass L1+L2), blocking. R1-proven.
__device__ __forceinline__ bf16x8 load16_sys(const unsigned short* p) {
    bf16x8 d;
    asm volatile("global_load_dwordx4 %0, %1, off sc0 sc1\n\t"
                 "s_waitcnt vmcnt(0)"
                 : "=v"(d) : "v"(p));
    return d;
}

// ---------------------------------------------------------------------------
// Flag sync — sc0 sc1 both directions (only verified-correct flavor).
// Steady-state posts are NO-DRAIN (R11-verified): data stores are issued
// before the flag store; consumer samples trail flag visibility by
// detect + load-RT. Prologue/epilogue posts keep real drains.
// R13: the consumer prefetch moved to P0 (flags were posted a full phase
// earlier by peers) -> ~2.3us of flight instead of ~1us -> P3 stall shrinks.
// ---------------------------------------------------------------------------
__device__ __forceinline__ void flag_prefetch(const unsigned int* fp, intx4& f) {
    asm volatile("global_load_dwordx4 %0, %1, off sc0 sc1"
                 : "=v"(f) : "v"(fp) : "memory");
}
__device__ __forceinline__ bool flag_ok(const intx4& f, unsigned int tgt) {
    return (unsigned int)f[0] >= tgt && (unsigned int)f[1] >= tgt &&
           (unsigned int)f[2] >= tgt && (unsigned int)f[3] >= tgt;
}
__device__ __forceinline__ void wait4(const unsigned int* fp, unsigned int tgt) {
    for (;;) {
        intx4 f;
        asm volatile("global_load_dwordx4 %0, %1, off sc0 sc1\n\t"
                     "s_waitcnt vmcnt(0)" : "=v"(f) : "v"(fp) : "memory");
        if (flag_ok(f, tgt)) return;
        __builtin_amdgcn_s_sleep(1);
    }
}
__device__ __forceinline__ void flag_post(unsigned int* p, unsigned int v) {
    asm volatile("global_store_dword %0, %1, off sc0 sc1" :: "v"(p), "v"(v) : "memory");
}

// ---------------------------------------------------------------------------
// prep: permuted bf16 weights, bf16 z / fc_w, fused permuted bias, zero flags.
// ---------------------------------------------------------------------------
__global__ void prep_kernel(const float* __restrict__ z,
                            const float* __restrict__ w_ih,
                            const float* __restrict__ w_hh,
                            const float* __restrict__ b_ih,
                            const float* __restrict__ b_hh,
                            const float* __restrict__ fc_w,
                            unsigned short* __restrict__ Bp_ih,
                            unsigned short* __restrict__ Bp_hh,
                            unsigned short* __restrict__ z_bf,
                            unsigned short* __restrict__ fcw_bf,
                            float* __restrict__ biasp,
                            unsigned int* __restrict__ cnt) {
    int i = blockIdx.x * blockDim.x + threadIdx.x;   // 2048*512 threads
    int col = i >> 9, k = i & 511;
    int jj = col >> 7, cc = col & 127;
    int gate = (cc >> 4) & 3;
    int hcl = ((cc >> 6) << 4) | (cc & 15);
    int p = gate * 512 + jj * 32 + hcl;
    Bp_hh[i] = f2bf(w_hh[p * 512 + k]);
    Bp_ih[i] = f2bf(w_ih[p * 512 + k]);
    z_bf[i]  = f2bf(z[i]);
    if (i < V_ * H_) fcw_bf[i] = f2bf(fc_w[i]);
    if (i < FOURH) {
        int j2 = i >> 7, c2 = i & 127;
        int g2 = (c2 >> 4) & 3;
        int h2 = ((c2 >> 6) << 4) | (c2 & 15);
        int p2 = g2 * 512 + j2 * 32 + h2;
        biasp[i] = b_ih[p2] + b_hh[p2];
    }
    // 32 groups x 64 uints: [0..7]=flagA, [8..15]=flagB. Zero all.
    if (i < 2048) cnt[i] = 0;
}

// ---------------------------------------------------------------------------
// Round-1-proven 128x128 (K=512, BK=64) tile core for the x-gates GEMM.
// ---------------------------------------------------------------------------
__device__ __forceinline__ void gemm_tile_r1(
        const unsigned short* __restrict__ Aglob,
        const unsigned short* __restrict__ Bglob,
        int arow0, int brow0,
        unsigned short* As, unsigned short* Bs,
        floatx4 acc[2][8], int w, int l) {
    const int lr = l >> 3;
    const int gl = (l & 7) ^ lr;
    const int ln = l & 15, lq = l >> 4, ls = l & 7;
    for (int kc = 0; kc < 8; ++kc) {
        const int kof = kc * 64 + gl * 8;
        #pragma unroll
        for (int q = 0; q < 4; ++q) {
            const int r0 = (w * 4 + q) * 8;
            global_to_lds16(Aglob + (size_t)(arow0 + r0 + lr) * 512 + kof, As + r0 * 64);
            global_to_lds16(Bglob + (size_t)(brow0 + r0 + lr) * 512 + kof, Bs + r0 * 64);
        }
        __syncthreads();
        #pragma unroll
        for (int kk = 0; kk < 2; ++kk) {
            bf16x8 a[2], b[8];
            #pragma unroll
            for (int mt = 0; mt < 2; ++mt) {
                const int m = 32 * w + 16 * mt + ln;
                const int g = kk * 4 + lq;
                a[mt] = *(const bf16x8*)(As + m * 64 + ((g ^ ls) * 8));
            }
            #pragma unroll
            for (int nt = 0; nt < 8; ++nt) {
                const int n = 16 * nt + ln;
                const int g = kk * 4 + lq;
                b[nt] = *(const bf16x8*)(Bs + n * 64 + ((g ^ ls) * 8));
            }
            #pragma unroll
            for (int mt = 0; mt < 2; ++mt)
                #pragma unroll
                for (int nt = 0; nt < 8; ++nt)
                    acc[mt][nt] = __builtin_amdgcn_mfma_f32_16x16x32_bf16(
                        a[mt], b[nt], acc[mt][nt], 0, 0, 0);
        }
        __syncthreads();
    }
}

__global__ void __launch_bounds__(256) xg_gemm_kernel(
        const unsigned short* __restrict__ z_bf,
        const unsigned short* __restrict__ Bp_ih,
        const float* __restrict__ biasp,
        float* __restrict__ xg) {
    __shared__ unsigned short As[128 * 64];
    __shared__ unsigned short Bs[128 * 64];
    const int bi = blockIdx.x, j = blockIdx.y;
    const int tid = threadIdx.x, w = tid >> 6, l = tid & 63;
    floatx4 acc[2][8];
    const floatx4 zf = {0.f, 0.f, 0.f, 0.f};
    for (int a1 = 0; a1 < 2; ++a1) for (int a2 = 0; a2 < 8; ++a2) acc[a1][a2] = zf;

    gemm_tile_r1(z_bf, Bp_ih, bi * 128, j * 128, As, Bs, acc, w, l);

    const int ln = l & 15, lq = l >> 4;
    #pragma unroll
    for (int mt = 0; mt < 2; ++mt)
        #pragma unroll
        for (int nt = 0; nt < 8; ++nt) {
            const int colp = j * 128 + nt * 16 + ln;
            const float bv = biasp[colp];
            #pragma unroll
            for (int r = 0; r < 4; ++r) {
                const int b = bi * 128 + 32 * w + 16 * mt + lq * 4 + r;
                xg[(size_t)b * FOURH + colp] = acc[mt][nt][r] + bv;
            }
        }
}

// ---------------------------------------------------------------------------
// Two-phase row-sliced LSTM phase body (R13 = R11 + P0 flag prefetch).
// Per-wave VM issue order per phase: [2 flag loads][4 out-stores][8 staged
// loads][1 h-store][wave0: 1 flag store]. In-order vmcnt retirement => at
// next P0: waves 1-3 vmcnt(1) retires everything through the staged loads
// while leaving the h-store in flight (wave 0: vmcnt(2) also leaves its flag
// store). The h-store ack + flag loads land under P3's vmcnt(0) with ~2.3us
// of commit+barrier+MFMA cover.
// ---------------------------------------------------------------------------
template<int HF>
__device__ __forceinline__ void phase_body(
        int t, bool first, bool last,
        int arow0, int j, int tid, int w, int l, int ln, int lq,
        bool my_half, int j16, int v, float fcb_v,
        unsigned short* hb0, unsigned short* hb1,
        unsigned int* flagp,
        unsigned short* Xlds, unsigned short* hlds,
        const unsigned short* __restrict__ fcw_bf,
        const bf16x8 (&bq)[16][4],
        floatx4 (&acc)[2][4], float (&cst)[2][4], const floatx4 (&xga)[2][4],
        floatx4& pacc, float* __restrict__ out,
        intx4 (&u)[8], intx4& fp0, intx4& fp1)
{
    const unsigned int V = (unsigned int)t + (unsigned int)HF;
    const int foff = 8 * (1 - HF);      // phase A confirms flagB (+8), B -> flagA (+0)
    unsigned short* hbt[2] = {hb0, hb1};
    const floatx4 zf = {0.f, 0.f, 0.f, 0.f};

    // P0: retire ONLY the staged loads (counted vmcnt; h-store stays in flight)
    if (first)      asm volatile("s_waitcnt vmcnt(0)" ::: "memory");
    else if (w == 0) asm volatile("s_waitcnt vmcnt(2)" ::: "memory");
    else            asm volatile("s_waitcnt vmcnt(1)" ::: "memory");
    __builtin_amdgcn_sched_barrier(0);

    // R13: prefetch peer flags HERE (they were posted a full phase ago at the
    // peers' opposite-phase P4) -> flight = commit + barrier + MFMA (~2.3us)
    if (!last) {
        flag_prefetch(flagp + foff,     fp0);
        flag_prefetch(flagp + foff + 4, fp1);
    }

    // P1: commit staged tile -> LDS
    {
        const int lr = l >> 3, sl = (l & 7) * 8;
        #pragma unroll
        for (int kc = 0; kc < 8; ++kc)
            *(intx4*)(Xlds + kc * 2048 + (w * 8 + lr) * 64 + sl) = u[kc];
    }
    __syncthreads();

    // P2: MFMA
    if (my_half) pacc = zf;
    #pragma unroll
    for (int s = 0; s < 16; ++s) {
        const int ga = (s & 1) * 4 + lq;
        const unsigned short* Ac = Xlds + (s >> 1) * 2048;
        bf16x8 af[2];
        #pragma unroll
        for (int mt = 0; mt < 2; ++mt)
            af[mt] = *(const bf16x8*)(Ac + (16 * mt + ln) * 64 + ((ga ^ (ln & 7)) * 8));
        #pragma unroll
        for (int mt = 0; mt < 2; ++mt)
            #pragma unroll
            for (int nt = 0; nt < 4; ++nt)
                acc[mt][nt] = __builtin_amdgcn_mfma_f32_16x16x32_bf16(
                    af[mt], bq[s][nt], acc[mt][nt], 0, 0, 0);
        if (my_half) {
            bf16x8 ap = *(const bf16x8*)(Ac + ((j16 & 31) + ln) * 64 + ((ga ^ (ln & 7)) * 8));
            bf16x8 bp = *(const bf16x8*)(fcw_bf + (size_t)v * 512 + s * 32 + lq * 8);
            pacc = __builtin_amdgcn_mfma_f32_16x16x32_bf16(ap, bp, pacc, 0, 0, 0);
        }
    }

    // P3: retire flag prefetch + previous h-store ack (covered); confirm;
    //     out[t-1]; issue next half's staged loads
    if (!last) {
        asm volatile("s_waitcnt vmcnt(0)" ::: "memory");
        __builtin_amdgcn_sched_barrier(0);
        if (!(flag_ok(fp0, V) && flag_ok(fp1, V))) {
            wait4(flagp + foff,     V);
            wait4(flagp + foff + 4, V);
        }
        if (my_half) {
            #pragma unroll
            for (int r = 0; r < 4; ++r) {
                const int b = arow0 + j16 + lq * 4 + r;
                out[(size_t)b * (T_ * V_) + (t - 1) * V_ + v] = fmaxf(pacc[r] + fcb_v, 0.0f);
            }
        }
        {   // issue next half's staged loads (gated by the flags just confirmed)
            const unsigned short* src = hbt[(t - 1 + HF) & 1]
                                      + (size_t)(arow0 + (1 - HF) * 32) * 512;
            const int lr = l >> 3;
            const int gl = (l & 7) ^ lr;
            #pragma unroll
            for (int kc = 0; kc < 8; ++kc) {
                const unsigned short* p = src + (size_t)(w * 8 + lr) * 512 + kc * 64 + gl * 8;
                asm volatile("global_load_dwordx4 %0, %1, off sc0 sc1"
                             : "=&v"(u[kc]) : "v"(p) : "memory");
            }
        }
    } else {
        asm volatile("s_waitcnt vmcnt(0)" ::: "memory");
        __builtin_amdgcn_sched_barrier(0);
        if (my_half) {
            #pragma unroll
            for (int r = 0; r < 4; ++r) {
                const int b = arow0 + j16 + lq * 4 + r;
                out[(size_t)b * (T_ * V_) + (t - 1) * V_ + v] = fmaxf(pacc[r] + fcb_v, 0.0f);
            }
        }
    }

    // P4: gates -> h_X(t); store; barrier; NO-DRAIN flag post (flagX = t+1)
    #pragma unroll
    for (int mt = 0; mt < 2; ++mt)
        #pragma unroll
        for (int r = 0; r < 4; ++r) {
            float iv = sigmoidf_(acc[mt][0][r] + xga[mt][0][r]);
            float fv = sigmoidf_(acc[mt][1][r] + xga[mt][1][r]);
            float gv = tanhf_  (acc[mt][2][r] + xga[mt][2][r]);
            float ov = sigmoidf_(acc[mt][3][r] + xga[mt][3][r]);
            float cn = fv * cst[mt][r] + iv * gv;
            cst[mt][r] = cn;
            hlds[(16 * mt + lq * 4 + r) * 64 + (16 * w + ln)] = f2bf(ov * tanhf_(cn));
        }
    #pragma unroll
    for (int mt = 0; mt < 2; ++mt)
        #pragma unroll
        for (int nt = 0; nt < 4; ++nt) acc[mt][nt] = zf;
    __syncthreads();
    {
        const int row = tid >> 3, seg = tid & 7;
        intx4 d = *(const intx4*)(hlds + row * 64 + seg * 8);
        const unsigned short* p = hbt[t & 1]
                                + (size_t)(arow0 + HF * 32 + row) * 512 + j * 64 + seg * 8;
        asm volatile("global_store_dwordx4 %0, %1, off sc0 sc1" :: "v"(p), "v"(d) : "memory");
    }
    __syncthreads();   // all waves' h-stores ISSUED before the flag
    if (tid == 0) flag_post(flagp + 8 * HF + j, (unsigned int)t + 1u);
}

// ---------------------------------------------------------------------------
// Persistent LSTM, 32 groups x 8 WGs, 64 rows x 256 cols per WG, rows split
// into two independent 32-row half-chains pipelined half a step apart.
// ---------------------------------------------------------------------------
__global__ void __launch_bounds__(256, 1) lstm_persistent(
        const unsigned short* __restrict__ Bp_hh,
        const unsigned short* __restrict__ fcw_bf,
        const float* __restrict__ xg,
        const float* __restrict__ fc_b,
        unsigned short* __restrict__ h0b,
        unsigned short* __restrict__ h1b,
        unsigned int* __restrict__ cnt,
        float* __restrict__ out) {
    __shared__ unsigned short Alds[8 * 2048];   // 32 KiB half-A staged tile
    __shared__ unsigned short Blds[8 * 2048];   // 32 KiB half-B staged tile
    __shared__ unsigned short hlds[2048];       //  4 KiB h transpose buffer

    const int bx = blockIdx.x;
    const int gi = bx & 31;
    const int j  = bx >> 5;                // 0..7
    const int tid = threadIdx.x;
    const int w = tid >> 6, l = tid & 63;
    const int ln = l & 15, lq = l >> 4;
    const bool jlt4 = (j < 4);
    const int j16 = j * 16;
    const int v = 16 * w + ln;
    const float fcb_v = fc_b[v];
    const int arow0 = gi * 64;
    const int colbase = j * 256 + (w >> 1) * 128 + (w & 1) * 64;
    unsigned int* flagp = cnt + gi * 64;   // [0..7]=flagA, [8..15]=flagB
    const floatx4 zf = {0.f, 0.f, 0.f, 0.f};
    const bool myA = jlt4 && (j < 2);      // projection rows in half A
    const bool myB = jlt4 && (j >= 2);     // projection rows in half B

    // ---- recurrent-weight fragments in registers (persistent) ----
    bf16x8 bq[16][4];
    {
        const unsigned short* bbase =
            Bp_hh + ((size_t)(colbase + ln)) * 512 + lq * 8;
        #pragma unroll
        for (int s = 0; s < 16; ++s)
            #pragma unroll
            for (int nt = 0; nt < 4; ++nt)
                bq[s][nt] = *(const bf16x8*)(bbase + (size_t)nt * 16 * 512 + s * 32);
    }

    // ---- x-gate tiles into registers, split by half ----
    floatx4 xgaA[2][4], xgaB[2][4];
    #pragma unroll
    for (int mt = 0; mt < 2; ++mt)
        #pragma unroll
        for (int nt = 0; nt < 4; ++nt)
            #pragma unroll
            for (int r = 0; r < 4; ++r) {
                const int ba = arow0 + 16 * mt + lq * 4 + r;
                const int bb = arow0 + 32 + 16 * mt + lq * 4 + r;
                xgaA[mt][nt][r] = xg[(size_t)ba * FOURH + colbase + 16 * nt + ln];
                xgaB[mt][nt][r] = xg[(size_t)bb * FOURH + colbase + 16 * nt + ln];
            }

    // ---- group stagger (R9, +2.8%): gi * ~0.4us one-time ----
    for (int d = 0; d < gi; ++d) __builtin_amdgcn_s_sleep(15);

    // ---- t = 0 for both halves: c0 = 0 -> h0 ----
    float cstA[2][4], cstB[2][4];
    floatx4 accA[2][4], accB[2][4];
    #pragma unroll
    for (int mt = 0; mt < 2; ++mt)
        #pragma unroll
        for (int nt = 0; nt < 4; ++nt) { accA[mt][nt] = zf; accB[mt][nt] = zf; }

    // half A
    #pragma unroll
    for (int mt = 0; mt < 2; ++mt)
        #pragma unroll
        for (int r = 0; r < 4; ++r) {
            float iv = sigmoidf_(xgaA[mt][0][r]);
            float gv = tanhf_  (xgaA[mt][2][r]);
            float ov = sigmoidf_(xgaA[mt][3][r]);
            float cv = iv * gv;
            cstA[mt][r] = cv;
            hlds[(16 * mt + lq * 4 + r) * 64 + (16 * w + ln)] = f2bf(ov * tanhf_(cv));
        }
    __syncthreads();
    {
        const int row = tid >> 3, seg = tid & 7;
        intx4 d = *(const intx4*)(hlds + row * 64 + seg * 8);
        const unsigned short* p = h0b + (size_t)(arow0 + row) * 512 + j * 64 + seg * 8;
        asm volatile("global_store_dwordx4 %0, %1, off sc0 sc1" :: "v"(p), "v"(d) : "memory");
    }
    __syncthreads();
    // half B
    #pragma unroll
    for (int mt = 0; mt < 2; ++mt)
        #pragma unroll
        for (int r = 0; r < 4; ++r) {
            float iv = sigmoidf_(xgaB[mt][0][r]);
            float gv = tanhf_  (xgaB[mt][2][r]);
            float ov = sigmoidf_(xgaB[mt][3][r]);
            float cv = iv * gv;
            cstB[mt][r] = cv;
            hlds[(16 * mt + lq * 4 + r) * 64 + (16 * w + ln)] = f2bf(ov * tanhf_(cv));
        }
    __syncthreads();
    {
        const int row = tid >> 3, seg = tid & 7;
        intx4 d = *(const intx4*)(hlds + row * 64 + seg * 8);
        const unsigned short* p = h0b + (size_t)(arow0 + 32 + row) * 512 + j * 64 + seg * 8;
        asm volatile("global_store_dwordx4 %0, %1, off sc0 sc1" :: "v"(p), "v"(d) : "memory");
    }
    asm volatile("s_waitcnt vmcnt(0)" ::: "memory");   // prologue keeps the drain
    __syncthreads();
    if (tid == 0) { flag_post(flagp + j, 1u); flag_post(flagp + 8 + j, 1u); }

    // gate + issue A(1)-loads
    wait4(flagp,     1u);
    wait4(flagp + 4, 1u);
    intx4 u[8];
    {
        const unsigned short* src = h0b + (size_t)arow0 * 512;
        const int lr = l >> 3;
        const int gl = (l & 7) ^ lr;
        #pragma unroll
        for (int kc = 0; kc < 8; ++kc) {
            const unsigned short* p = src + (size_t)(w * 8 + lr) * 512 + kc * 64 + gl * 8;
            asm volatile("global_load_dwordx4 %0, %1, off sc0 sc1"
                         : "=&v"(u[kc]) : "v"(p) : "memory");
        }
    }

    floatx4 pacc = zf;
    intx4 fp0, fp1;
    #pragma unroll 1
    for (int t = 1; t < T_; ++t) {
        phase_body<0>(t, t == 1, false, arow0, j, tid, w, l, ln, lq, myA, j16, v, fcb_v,
                      h0b, h1b, flagp, Alds, hlds, fcw_bf, bq,
                      accA, cstA, xgaA, pacc, out, u, fp0, fp1);
        phase_body<1>(t, false, t == T_ - 1, arow0, j, tid, w, l, ln, lq, myB, j16, v, fcb_v,
                      h0b, h1b, flagp, Blds, hlds, fcw_bf, bq,
                      accB, cstB, xgaB, pacc, out, u, fp0, fp1);
    }

    // ---- epilogue: drain everything, re-post final flags (durable) ----
    asm volatile("s_waitcnt vmcnt(0)" ::: "memory");
    __syncthreads();
    if (tid == 0) {
        flag_post(flagp + j,     (unsigned int)T_);
        flag_post(flagp + 8 + j, (unsigned int)T_);
    }

    // ---- final projection of h_{T-1} ----
    if (jlt4) {
        const int hf = (j >= 2);
        wait4(flagp + 8 * hf,     (unsigned int)T_);
        wait4(flagp + 8 * hf + 4, (unsigned int)T_);
        const unsigned short* hlast = h1b;        // hb[(T_-1)&1] = hb1
        floatx4 pa = zf;
        const int ar = arow0 + j16 + ln;
        #pragma unroll
        for (int kc = 0; kc < 16; ++kc) {
            const int k = kc * 32 + lq * 8;
            bf16x8 a = load16_sys(hlast + (size_t)ar * 512 + k);
            bf16x8 b = *(const bf16x8*)(fcw_bf + (size_t)v * 512 + k);
            pa = __builtin_amdgcn_mfma_f32_16x16x32_bf16(a, b, pa, 0, 0, 0);
        }
        #pragma unroll
        for (int r = 0; r < 4; ++r) {
            const int b = arow0 + j16 + lq * 4 + r;
            out[(size_t)b * (T_ * V_) + (T_ - 1) * V_ + v] = fmaxf(pa[r] + fcb_v, 0.0f);
        }
    }
}

// ---------------------------------------------------------------------------
extern "C" void kernel_launch(void* const* d_in, const int* in_sizes, int n_in,
                              void* d_out, int out_size, void* d_ws, size_t ws_size,
                              hipStream_t stream) {
    const float* z    = (const float*)d_in[0];
    const float* w_ih = (const float*)d_in[1];
    const float* w_hh = (const float*)d_in[2];
    const float* b_ih = (const float*)d_in[3];
    const float* b_hh = (const float*)d_in[4];
    const float* fc_w = (const float*)d_in[5];
    const float* fc_b = (const float*)d_in[6];
    float* out = (float*)d_out;

    char* ws = (char*)d_ws;
    size_t o = 0;
    auto take = [&](size_t bytes) { char* p = ws + o; o += (bytes + 255) & ~(size_t)255; return p; };
    unsigned short* Bp_hh  = (unsigned short*)take((size_t)FOURH * H_ * 2);
    unsigned short* Bp_ih  = (unsigned short*)take((size_t)FOURH * H_ * 2);
    unsigned short* z_bf   = (unsigned short*)take((size_t)B_ * H_ * 2);
    unsigned short* fcw_bf = (unsigned short*)take((size_t)V_ * H_ * 2);
    float*          biasp  = (float*)take((size_t)FOURH * 4);
    unsigned short* hbuf0  = (unsigned short*)take((size_t)B_ * H_ * 2);
    unsigned short* hbuf1  = (unsigned short*)take((size_t)B_ * H_ * 2);
    unsigned int*   cnt    = (unsigned int*)take(32 * 256);   // 32 groups x 64 uints
    float*          xg     = (float*)take((size_t)B_ * FOURH * 4);

    prep_kernel<<<(B_ * H_) / 256, 256, 0, stream>>>(z, w_ih, w_hh, b_ih, b_hh, fc_w,
                                                     Bp_ih, Bp_hh, z_bf, fcw_bf, biasp, cnt);
    xg_gemm_kernel<<<dim3(16, 16), 256, 0, stream>>>(z_bf, Bp_ih, biasp, xg);
    lstm_persistent<<<256, 256, 0, stream>>>(Bp_hh, fcw_bf, xg, fc_b,
                                             hbuf0, hbuf1, cnt, out);
}